// Round 2
// baseline (137.327 us; speedup 1.0000x reference)
//
#include <hip/hip_runtime.h>

#define N_KER 64
#define K_PTS 16
#define LOG2E 1.44269504088896340736f

// Thread layout: block = 256 threads = 4 points x 64 kernels.
// lane (tid&63) = kernel index m  -> coalesced out writes, conflict-free LDS.
// Scaled kernel staged in LDS as [l][d][m] so lane-m reads are stride-1.
__global__ __launch_bounds__(256) void corr_kernel(
    const float* __restrict__ normal,
    const int*   __restrict__ neighbour,
    const float* __restrict__ kern,
    float*       __restrict__ out,
    int n)
{
    __shared__ float ks[K_PTS * 3 * N_KER];   // [l][d][m] = 2*log2e*kernel[m][l][d]
    __shared__ float k2s[K_PTS * N_KER];      // [l][m]    = -log2e*||kernel[m][l]||^2

    const int tid = threadIdx.x;

    // ---- stage scaled kernel into LDS (12 KB + 4 KB) ----
    for (int idx = tid; idx < N_KER * K_PTS * 3; idx += 256) {
        int m = idx / (K_PTS * 3);
        int r = idx % (K_PTS * 3);
        int l = r / 3, d = r % 3;
        ks[(l * 3 + d) * N_KER + m] = 2.0f * LOG2E * kern[idx];
    }
    for (int j = tid; j < N_KER * K_PTS; j += 256) {
        int m = j / K_PTS, l = j % K_PTS;
        const float* kp = kern + (m * K_PTS + l) * 3;
        float x = kp[0], y = kp[1], z = kp[2];
        k2s[l * N_KER + m] = -LOG2E * (x * x + y * y + z * z);
    }
    __syncthreads();

    const int i = blockIdx.x * 4 + (tid >> 6);
    const int m = tid & 63;
    if (i >= n) return;

    // ---- gather self + 3 neighbors (wave-uniform addresses -> broadcast) ----
    const int ia = neighbour[i * 3 + 0];
    const int ib = neighbour[i * 3 + 1];
    const int ic = neighbour[i * 3 + 2];
    int idxs[4] = { i, ia, ib, ic };

    float gx[4], gy[4], gz[4], a[4];
    #pragma unroll
    for (int p = 0; p < 4; ++p) {
        int q = idxs[p];
        float x = normal[q * 3 + 0];
        float y = normal[q * 3 + 1];
        float z = normal[q * 3 + 2];
        gx[p] = x; gy[p] = y; gz[p] = z;
        a[p] = -LOG2E * (x * x + y * y + z * z);
    }

    // ---- main loop: 16 kernel points x 4 gathered points = 64 exps/thread ----
    float acc0 = 0.f, acc1 = 0.f, acc2 = 0.f, acc3 = 0.f;
    #pragma unroll
    for (int l = 0; l < K_PTS; ++l) {
        float kx = ks[(l * 3 + 0) * N_KER + m];
        float ky = ks[(l * 3 + 1) * N_KER + m];
        float kz = ks[(l * 3 + 2) * N_KER + m];
        float kc = k2s[l * N_KER + m];
        // arg = -log2e * d2 = a_p + kc + gx*kx + gy*ky + gz*kz
        acc0 += __builtin_amdgcn_exp2f(fmaf(gx[0], kx, fmaf(gy[0], ky, fmaf(gz[0], kz, a[0] + kc))));
        acc1 += __builtin_amdgcn_exp2f(fmaf(gx[1], kx, fmaf(gy[1], ky, fmaf(gz[1], kz, a[1] + kc))));
        acc2 += __builtin_amdgcn_exp2f(fmaf(gx[2], kx, fmaf(gy[2], ky, fmaf(gz[2], kz, a[2] + kc))));
        acc3 += __builtin_amdgcn_exp2f(fmaf(gx[3], kx, fmaf(gy[3], ky, fmaf(gz[3], kz, a[3] + kc))));
    }

    // out[i,m] = (1/(K*4)) * (1/(2*sigma^2)) * sum exp(-d2) = sum * 1/128
    out[(size_t)i * N_KER + m] = (acc0 + acc1 + acc2 + acc3) * (1.0f / 128.0f);
}

extern "C" void kernel_launch(void* const* d_in, const int* in_sizes, int n_in,
                              void* d_out, int out_size, void* d_ws, size_t ws_size,
                              hipStream_t stream) {
    const float* normal    = (const float*)d_in[0];
    const int*   neighbour = (const int*)d_in[1];
    const float* kern      = (const float*)d_in[2];
    float*       out       = (float*)d_out;

    int n = in_sizes[0] / 3;
    int blocks = (n + 3) / 4;   // 4 points per block
    corr_kernel<<<blocks, 256, 0, stream>>>(normal, neighbour, kern, out, n);
}

// Round 3
// 100.210 us; speedup vs baseline: 1.3704x; 1.3704x over previous
//
#include <hip/hip_runtime.h>

#define N_KER 64
#define K_PTS 16
#define LOG2E 1.44269504088896340736f

// block = 256 = 4 waves; each wave processes 2 output points across all 64
// kernels (lane = kernel index m -> coalesced out writes).
// Kernel table staged once in LDS as float4 [l][m] = {2*log2e*k.xyz,
// -log2e*||k||^2}; per-lane 16B accesses are bank-conflict-free (lane i's
// 16B spans banks 4i..4i+3 within each 8-lane phase).
// Math: exp(-d2) = exp2(-log2e*||g||^2) * exp2(kc + g . (2*log2e*k)),
// with the first factor hoisted out of the l-sum (saves 4 VALU/l).
__global__ __launch_bounds__(256) void corr_kernel(
    const float* __restrict__ normal,
    const int*   __restrict__ neighbour,
    const float* __restrict__ kern,
    float*       __restrict__ out,
    int n)
{
    __shared__ float4 ksp[K_PTS * N_KER];   // 16 KB, [l][m]

    const int tid = threadIdx.x;

    // ---- staging: thread -> (l,m) pair, one float4 write. 4 iterations.
    // consecutive lanes -> consecutive m -> consecutive 16B addrs: no conflicts.
    #pragma unroll
    for (int it = 0; it < 4; ++it) {
        int j = it * 256 + tid;            // 0..1023
        int m = j & 63;
        int l = j >> 6;
        const float* kp = kern + (m * K_PTS + l) * 3;
        float x = kp[0], y = kp[1], z = kp[2];
        ksp[l * N_KER + m] = make_float4(2.0f * LOG2E * x,
                                         2.0f * LOG2E * y,
                                         2.0f * LOG2E * z,
                                         -LOG2E * (x * x + y * y + z * z));
    }
    __syncthreads();

    const int wave = tid >> 6;
    const int m    = tid & 63;
    const int i0   = blockIdx.x * 8 + wave * 2;   // 2 output points per wave

    // ---- gather self + 3 neighbors for 2 output points (8 gathered pts).
    // All addresses are wave-uniform -> broadcast loads.
    int idxs[8];
    #pragma unroll
    for (int o = 0; o < 2; ++o) {
        int i = min(i0 + o, n - 1);
        idxs[o * 4 + 0] = i;
        idxs[o * 4 + 1] = neighbour[i * 3 + 0];
        idxs[o * 4 + 2] = neighbour[i * 3 + 1];
        idxs[o * 4 + 3] = neighbour[i * 3 + 2];
    }

    float gx[8], gy[8], gz[8], ea[8], acc[8];
    #pragma unroll
    for (int p = 0; p < 8; ++p) {
        int q = idxs[p];
        float x = normal[q * 3 + 0];
        float y = normal[q * 3 + 1];
        float z = normal[q * 3 + 2];
        gx[p] = x; gy[p] = y; gz[p] = z;
        ea[p] = __builtin_amdgcn_exp2f(-LOG2E * (x * x + y * y + z * z));
        acc[p] = 0.0f;
    }

    // ---- main loop: 16 l-steps x 8 gathered points = 128 exps/thread.
    // Per l: 1 ds_read_b128 + 24 fma + 8 exp + 8 add.
    #pragma unroll
    for (int l = 0; l < K_PTS; ++l) {
        float4 k4 = ksp[l * N_KER + m];
        #pragma unroll
        for (int p = 0; p < 8; ++p)
            acc[p] += __builtin_amdgcn_exp2f(
                fmaf(gx[p], k4.x, fmaf(gy[p], k4.y, fmaf(gz[p], k4.z, k4.w))));
    }

    // ---- epilogue: out[i,m] = (1/128) * sum_p ea_p * acc_p
    #pragma unroll
    for (int o = 0; o < 2; ++o) {
        int i = i0 + o;
        if (i < n) {
            float s = ea[o * 4 + 0] * acc[o * 4 + 0]
                    + ea[o * 4 + 1] * acc[o * 4 + 1]
                    + ea[o * 4 + 2] * acc[o * 4 + 2]
                    + ea[o * 4 + 3] * acc[o * 4 + 3];
            out[(size_t)i * N_KER + m] = s * (1.0f / 128.0f);
        }
    }
}

extern "C" void kernel_launch(void* const* d_in, const int* in_sizes, int n_in,
                              void* d_out, int out_size, void* d_ws, size_t ws_size,
                              hipStream_t stream) {
    const float* normal    = (const float*)d_in[0];
    const int*   neighbour = (const int*)d_in[1];
    const float* kern      = (const float*)d_in[2];
    float*       out       = (float*)d_out;

    int n = in_sizes[0] / 3;
    int blocks = (n + 7) / 8;   // 8 points per block (2 per wave)
    corr_kernel<<<blocks, 256, 0, stream>>>(normal, neighbour, kern, out, n);
}

// Round 4
// 97.030 us; speedup vs baseline: 1.4153x; 1.0328x over previous
//
#include <hip/hip_runtime.h>

#define N_KER 64
#define K_PTS 16
#define LOG2E 1.44269504088896340736f

// block = 256 = 4 waves; each wave = 1 output point x 64 kernels (lane = m).
// Kernel table in LDS as float4 [l][m] = {2*log2e*k.xyz, -log2e*||k||^2};
// staging and main-loop reads are bank-conflict-free (verified R3: 0 conflicts).
// Math: exp(-d2) = exp2(-log2e*||g||^2) * exp2(k4.w + g . k4.xyz), ea hoisted.
// __launch_bounds__(256, 8): pin VGPR <= 64 — R3 showed VGPR=72 halves
// occupancy (m69 boundary) and that, not LDS or VALU, was the limiter.
__global__ __launch_bounds__(256, 8) void corr_kernel(
    const float* __restrict__ normal,
    const int*   __restrict__ neighbour,
    const float* __restrict__ kern,
    float*       __restrict__ out,
    int n)
{
    __shared__ float4 ksp[K_PTS * N_KER];   // 16 KB

    const int tid = threadIdx.x;

    // ---- staging: thread -> (l,m), one float4 write, consecutive lanes ->
    // consecutive 16B addrs: conflict-free.
    #pragma unroll
    for (int it = 0; it < 4; ++it) {
        int j = it * 256 + tid;            // 0..1023
        int m = j & 63;
        int l = j >> 6;
        const float* kp = kern + (m * K_PTS + l) * 3;
        float x = kp[0], y = kp[1], z = kp[2];
        ksp[l * N_KER + m] = make_float4(2.0f * LOG2E * x,
                                         2.0f * LOG2E * y,
                                         2.0f * LOG2E * z,
                                         -LOG2E * (x * x + y * y + z * z));
    }
    __syncthreads();

    const int wave = tid >> 6;
    const int m    = tid & 63;
    const int i    = blockIdx.x * 4 + wave;   // 1 output point per wave
    if (i >= n) return;

    // ---- gather self + 3 neighbors (wave-uniform addrs -> broadcast loads)
    const int ia = neighbour[i * 3 + 0];
    const int ib = neighbour[i * 3 + 1];
    const int ic = neighbour[i * 3 + 2];
    int idxs[4] = { i, ia, ib, ic };

    float gx[4], gy[4], gz[4], ea[4], acc[4];
    #pragma unroll
    for (int p = 0; p < 4; ++p) {
        int q = idxs[p];
        float x = normal[q * 3 + 0];
        float y = normal[q * 3 + 1];
        float z = normal[q * 3 + 2];
        gx[p] = x; gy[p] = y; gz[p] = z;
        ea[p] = __builtin_amdgcn_exp2f(-LOG2E * (x * x + y * y + z * z));
        acc[p] = 0.0f;
    }

    // ---- main loop: 16 l-steps x 4 points = 64 exps/thread.
    // Per l per wave: 1 ds_read_b128 (12cy LDS pipe) | 16 VALU (32cy) | 4 exp
    // (32cy trans) — balanced; needs >=4 waves/SIMD to overlap, hence the cap.
    // unroll 4 (not 16) so ds_read results aren't all hoisted into VGPRs.
    #pragma unroll 4
    for (int l = 0; l < K_PTS; ++l) {
        float4 k4 = ksp[l * N_KER + m];
        #pragma unroll
        for (int p = 0; p < 4; ++p)
            acc[p] += __builtin_amdgcn_exp2f(
                fmaf(gx[p], k4.x, fmaf(gy[p], k4.y, fmaf(gz[p], k4.z, k4.w))));
    }

    // ---- epilogue: out[i,m] = (1/128) * sum_p ea_p * acc_p; coalesced 256B/wave
    float s = ea[0] * acc[0] + ea[1] * acc[1] + ea[2] * acc[2] + ea[3] * acc[3];
    out[(size_t)i * N_KER + m] = s * (1.0f / 128.0f);
}

extern "C" void kernel_launch(void* const* d_in, const int* in_sizes, int n_in,
                              void* d_out, int out_size, void* d_ws, size_t ws_size,
                              hipStream_t stream) {
    const float* normal    = (const float*)d_in[0];
    const int*   neighbour = (const int*)d_in[1];
    const float* kern      = (const float*)d_in[2];
    float*       out       = (float*)d_out;

    int n = in_sizes[0] / 3;
    int blocks = (n + 3) / 4;   // 4 points per block (1 per wave)
    corr_kernel<<<blocks, 256, 0, stream>>>(normal, neighbour, kern, out, n);
}

// Round 5
// 88.095 us; speedup vs baseline: 1.5589x; 1.1014x over previous
//
#include <hip/hip_runtime.h>

#define N_KER 64
#define K_PTS 16
#define LOG2E 1.44269504088896340736f

// ============================================================================
// Key algebra: out[i][m] = (1/128) * (S[i][m] + S[a][m] + S[b][m] + S[c][m])
// where S[q][m] = sum_l exp(-||g_q - k[m][l]||^2) depends on q ALONE.
// The fused kernel (R2-R4) recomputed S 4x (once per point listing q as a
// neighbor) -> 204.8M exps. Split: phase1 computes S once (51.2M exps, the
// issue-bound part), phase2 is a memory-bound gather-add.
// ============================================================================

// ---- Phase 1: S[q][m], thread = (q,m), lane = m, 2 q per wave ----
// Kernel table in LDS as float4 [l][m] = {2*log2e*k.xyz, -log2e*||k||^2};
// staging & reads bank-conflict-free (verified R3/R4: SQ_LDS_BANK_CONFLICT=0).
// exp(-d2) = exp2(-log2e*||g||^2) * exp2(k4.w + g . k4.xyz), first factor
// hoisted out of the l-sum.
__global__ __launch_bounds__(256, 8) void corr_phase1(
    const float* __restrict__ normal,
    const float* __restrict__ kern,
    float*       __restrict__ S,
    int n)
{
    __shared__ float4 ksp[K_PTS * N_KER];   // 16 KB

    const int tid = threadIdx.x;
    #pragma unroll
    for (int it = 0; it < 4; ++it) {
        int j = it * 256 + tid;            // 0..1023 -> (l,m)
        int m = j & 63;
        int l = j >> 6;
        const float* kp = kern + (m * K_PTS + l) * 3;
        float x = kp[0], y = kp[1], z = kp[2];
        ksp[l * N_KER + m] = make_float4(2.0f * LOG2E * x,
                                         2.0f * LOG2E * y,
                                         2.0f * LOG2E * z,
                                         -LOG2E * (x * x + y * y + z * z));
    }
    __syncthreads();

    const int wave = tid >> 6;
    const int m    = tid & 63;
    const int q0   = blockIdx.x * 8 + wave * 2;    // 2 points per wave
    const int qa   = min(q0,     n - 1);
    const int qb   = min(q0 + 1, n - 1);

    // wave-uniform addresses -> broadcast loads
    float ax = normal[qa * 3 + 0], ay = normal[qa * 3 + 1], az = normal[qa * 3 + 2];
    float bx = normal[qb * 3 + 0], by = normal[qb * 3 + 1], bz = normal[qb * 3 + 2];
    float ea = __builtin_amdgcn_exp2f(-LOG2E * (ax * ax + ay * ay + az * az));
    float eb = __builtin_amdgcn_exp2f(-LOG2E * (bx * bx + by * by + bz * bz));

    float acc0 = 0.0f, acc1 = 0.0f;
    // 16 l-steps, 2 exps per ds_read_b128. unroll 4: VGPR moderation.
    #pragma unroll 4
    for (int l = 0; l < K_PTS; ++l) {
        float4 k4 = ksp[l * N_KER + m];
        acc0 += __builtin_amdgcn_exp2f(
            fmaf(ax, k4.x, fmaf(ay, k4.y, fmaf(az, k4.z, k4.w))));
        acc1 += __builtin_amdgcn_exp2f(
            fmaf(bx, k4.x, fmaf(by, k4.y, fmaf(bz, k4.z, k4.w))));
    }

    if (q0     < n) S[(size_t)q0       * N_KER + m] = ea * acc0;
    if (q0 + 1 < n) S[(size_t)(q0 + 1) * N_KER + m] = eb * acc1;
}

// ---- Phase 2: out = (S[i] + S[a] + S[b] + S[c]) / 128, float2/thread ----
// Lane-consecutive m -> all 4 reads and the write are coalesced; neighbour
// loads are wave-uniform (i constant across a wave's 64-element m-range...
// each wave covers 2 points, 2 uniform index groups). Table is L3-resident.
__global__ __launch_bounds__(256) void corr_phase2(
    const float2* __restrict__ S2,
    const int*    __restrict__ neighbour,
    float2*       __restrict__ out2,
    int n)
{
    int t = blockIdx.x * 256 + threadIdx.x;        // float2 element index
    int total2 = n * (N_KER / 2);
    if (t >= total2) return;
    int i  = t >> 5;                               // t*2 >> 6
    int h  = t & 31;                               // m/2 within point
    int a = neighbour[i * 3 + 0];
    int b = neighbour[i * 3 + 1];
    int c = neighbour[i * 3 + 2];
    float2 s0 = S2[t];
    float2 s1 = S2[(size_t)a * 32 + h];
    float2 s2 = S2[(size_t)b * 32 + h];
    float2 s3 = S2[(size_t)c * 32 + h];
    float2 r;
    r.x = (s0.x + s1.x + s2.x + s3.x) * (1.0f / 128.0f);
    r.y = (s0.y + s1.y + s2.y + s3.y) * (1.0f / 128.0f);
    out2[t] = r;
}

// ---- Fallback (R4 kernel, proven): used only if ws_size < n*64*4 ----
__global__ __launch_bounds__(256, 8) void corr_fused(
    const float* __restrict__ normal,
    const int*   __restrict__ neighbour,
    const float* __restrict__ kern,
    float*       __restrict__ out,
    int n)
{
    __shared__ float4 ksp[K_PTS * N_KER];
    const int tid = threadIdx.x;
    #pragma unroll
    for (int it = 0; it < 4; ++it) {
        int j = it * 256 + tid;
        int m = j & 63;
        int l = j >> 6;
        const float* kp = kern + (m * K_PTS + l) * 3;
        float x = kp[0], y = kp[1], z = kp[2];
        ksp[l * N_KER + m] = make_float4(2.0f * LOG2E * x, 2.0f * LOG2E * y,
                                         2.0f * LOG2E * z,
                                         -LOG2E * (x * x + y * y + z * z));
    }
    __syncthreads();
    const int wave = tid >> 6;
    const int m    = tid & 63;
    const int i    = blockIdx.x * 4 + wave;
    if (i >= n) return;
    const int ia = neighbour[i * 3 + 0];
    const int ib = neighbour[i * 3 + 1];
    const int ic = neighbour[i * 3 + 2];
    int idxs[4] = { i, ia, ib, ic };
    float gx[4], gy[4], gz[4], ea[4], acc[4];
    #pragma unroll
    for (int p = 0; p < 4; ++p) {
        int q = idxs[p];
        float x = normal[q * 3 + 0];
        float y = normal[q * 3 + 1];
        float z = normal[q * 3 + 2];
        gx[p] = x; gy[p] = y; gz[p] = z;
        ea[p] = __builtin_amdgcn_exp2f(-LOG2E * (x * x + y * y + z * z));
        acc[p] = 0.0f;
    }
    #pragma unroll 4
    for (int l = 0; l < K_PTS; ++l) {
        float4 k4 = ksp[l * N_KER + m];
        #pragma unroll
        for (int p = 0; p < 4; ++p)
            acc[p] += __builtin_amdgcn_exp2f(
                fmaf(gx[p], k4.x, fmaf(gy[p], k4.y, fmaf(gz[p], k4.z, k4.w))));
    }
    float s = ea[0] * acc[0] + ea[1] * acc[1] + ea[2] * acc[2] + ea[3] * acc[3];
    out[(size_t)i * N_KER + m] = s * (1.0f / 128.0f);
}

extern "C" void kernel_launch(void* const* d_in, const int* in_sizes, int n_in,
                              void* d_out, int out_size, void* d_ws, size_t ws_size,
                              hipStream_t stream) {
    const float* normal    = (const float*)d_in[0];
    const int*   neighbour = (const int*)d_in[1];
    const float* kern      = (const float*)d_in[2];
    float*       out       = (float*)d_out;

    int n = in_sizes[0] / 3;
    size_t need = (size_t)n * N_KER * sizeof(float);

    if (ws_size >= need) {
        float* S = (float*)d_ws;
        int blocks1 = (n + 7) / 8;                     // 2 q/wave, 4 waves
        corr_phase1<<<blocks1, 256, 0, stream>>>(normal, kern, S, n);
        int total2  = n * (N_KER / 2);
        int blocks2 = (total2 + 255) / 256;
        corr_phase2<<<blocks2, 256, 0, stream>>>((const float2*)S, neighbour,
                                                 (float2*)out, n);
    } else {
        int blocks = (n + 3) / 4;
        corr_fused<<<blocks, 256, 0, stream>>>(normal, neighbour, kern, out, n);
    }
}

// Round 6
// 81.633 us; speedup vs baseline: 1.6823x; 1.0792x over previous
//
#include <hip/hip_runtime.h>
#include <hip/hip_fp16.h>

#define N_KER 64
#define K_PTS 16
#define LOG2E 1.44269504088896340736f

// ============================================================================
// out[i][m] = (1/128) * (S[i][m] + S[a][m] + S[b][m] + S[c][m]),
// S[q][m] = sum_l exp(-||g_q - k[m][l]||^2)  — computed ONCE per point
// (phase1, issue-bound, 51.2M exps) then gather-added (phase2, memory-bound).
// R6: S stored as f16 (values in [0,16], quantization error ~2.5e-4 on out,
// threshold 3.4e-3) -> phase2 traffic 64->38 MB and 6.4 MB table is far more
// L2-resident. Phase1 at 4 points/wave halves ds_reads + staging dispatches.
// ============================================================================

// ---- Phase 1: S[q][m] in f16; lane = m; 4 points per wave ----
__global__ __launch_bounds__(256, 8) void corr_phase1(
    const float* __restrict__ normal,
    const float* __restrict__ kern,
    __half*      __restrict__ S,
    int n)
{
    __shared__ float4 ksp[K_PTS * N_KER];   // 16 KB, [l][m], conflict-free (R3/R4: 0)

    const int tid = threadIdx.x;
    #pragma unroll
    for (int it = 0; it < 4; ++it) {
        int j = it * 256 + tid;            // 0..1023 -> (l,m)
        int m = j & 63;
        int l = j >> 6;
        const float* kp = kern + (m * K_PTS + l) * 3;
        float x = kp[0], y = kp[1], z = kp[2];
        ksp[l * N_KER + m] = make_float4(2.0f * LOG2E * x,
                                         2.0f * LOG2E * y,
                                         2.0f * LOG2E * z,
                                         -LOG2E * (x * x + y * y + z * z));
    }
    __syncthreads();

    const int wave = tid >> 6;
    const int m    = tid & 63;
    const int q0   = blockIdx.x * 16 + wave * 4;   // 4 points per wave

    float gx[4], gy[4], gz[4], ea[4], acc[4];
    #pragma unroll
    for (int p = 0; p < 4; ++p) {
        int q = min(q0 + p, n - 1);
        float x = normal[q * 3 + 0];    // wave-uniform -> broadcast loads
        float y = normal[q * 3 + 1];
        float z = normal[q * 3 + 2];
        gx[p] = x; gy[p] = y; gz[p] = z;
        ea[p] = __builtin_amdgcn_exp2f(-LOG2E * (x * x + y * y + z * z));
        acc[p] = 0.0f;
    }

    // 16 l-steps x 4 points: 1 ds_read_b128 -> 4 exps. unroll 4 keeps VGPR
    // under the 64 boundary (R3 lesson: crossing it halves occupancy).
    #pragma unroll 4
    for (int l = 0; l < K_PTS; ++l) {
        float4 k4 = ksp[l * N_KER + m];
        #pragma unroll
        for (int p = 0; p < 4; ++p)
            acc[p] += __builtin_amdgcn_exp2f(
                fmaf(gx[p], k4.x, fmaf(gy[p], k4.y, fmaf(gz[p], k4.z, k4.w))));
    }

    #pragma unroll
    for (int p = 0; p < 4; ++p)
        if (q0 + p < n)                     // 128B/wave coalesced f16 store
            S[(size_t)(q0 + p) * N_KER + m] = __float2half(ea[p] * acc[p]);
}

// ---- Phase 2: out = (S[i]+S[a]+S[b]+S[c]) / 128; __half2 per thread ----
// t>>5 = point, t&31 = half2 slot; each gathered row is 32 lanes x 4B = 128B
// contiguous. Self-read + write fully coalesced.
__global__ __launch_bounds__(256) void corr_phase2(
    const __half2* __restrict__ S2,
    const int*     __restrict__ neighbour,
    float2*        __restrict__ out2,
    int n)
{
    int t = blockIdx.x * 256 + threadIdx.x;
    int total2 = n * (N_KER / 2);
    if (t >= total2) return;
    int i = t >> 5;
    int h = t & 31;
    int a = neighbour[i * 3 + 0];
    int b = neighbour[i * 3 + 1];
    int c = neighbour[i * 3 + 2];
    float2 s0 = __half22float2(S2[t]);
    float2 s1 = __half22float2(S2[(size_t)a * 32 + h]);
    float2 s2 = __half22float2(S2[(size_t)b * 32 + h]);
    float2 s3 = __half22float2(S2[(size_t)c * 32 + h]);
    float2 r;
    r.x = (s0.x + s1.x + s2.x + s3.x) * (1.0f / 128.0f);
    r.y = (s0.y + s1.y + s2.y + s3.y) * (1.0f / 128.0f);
    out2[t] = r;
}

// ---- Fallback (R4 fused kernel, proven) if ws too small ----
__global__ __launch_bounds__(256, 8) void corr_fused(
    const float* __restrict__ normal,
    const int*   __restrict__ neighbour,
    const float* __restrict__ kern,
    float*       __restrict__ out,
    int n)
{
    __shared__ float4 ksp[K_PTS * N_KER];
    const int tid = threadIdx.x;
    #pragma unroll
    for (int it = 0; it < 4; ++it) {
        int j = it * 256 + tid;
        int m = j & 63;
        int l = j >> 6;
        const float* kp = kern + (m * K_PTS + l) * 3;
        float x = kp[0], y = kp[1], z = kp[2];
        ksp[l * N_KER + m] = make_float4(2.0f * LOG2E * x, 2.0f * LOG2E * y,
                                         2.0f * LOG2E * z,
                                         -LOG2E * (x * x + y * y + z * z));
    }
    __syncthreads();
    const int wave = tid >> 6;
    const int m    = tid & 63;
    const int i    = blockIdx.x * 4 + wave;
    if (i >= n) return;
    const int ia = neighbour[i * 3 + 0];
    const int ib = neighbour[i * 3 + 1];
    const int ic = neighbour[i * 3 + 2];
    int idxs[4] = { i, ia, ib, ic };
    float gx[4], gy[4], gz[4], ea[4], acc[4];
    #pragma unroll
    for (int p = 0; p < 4; ++p) {
        int q = idxs[p];
        float x = normal[q * 3 + 0];
        float y = normal[q * 3 + 1];
        float z = normal[q * 3 + 2];
        gx[p] = x; gy[p] = y; gz[p] = z;
        ea[p] = __builtin_amdgcn_exp2f(-LOG2E * (x * x + y * y + z * z));
        acc[p] = 0.0f;
    }
    #pragma unroll 4
    for (int l = 0; l < K_PTS; ++l) {
        float4 k4 = ksp[l * N_KER + m];
        #pragma unroll
        for (int p = 0; p < 4; ++p)
            acc[p] += __builtin_amdgcn_exp2f(
                fmaf(gx[p], k4.x, fmaf(gy[p], k4.y, fmaf(gz[p], k4.z, k4.w))));
    }
    float s = ea[0] * acc[0] + ea[1] * acc[1] + ea[2] * acc[2] + ea[3] * acc[3];
    out[(size_t)i * N_KER + m] = s * (1.0f / 128.0f);
}

extern "C" void kernel_launch(void* const* d_in, const int* in_sizes, int n_in,
                              void* d_out, int out_size, void* d_ws, size_t ws_size,
                              hipStream_t stream) {
    const float* normal    = (const float*)d_in[0];
    const int*   neighbour = (const int*)d_in[1];
    const float* kern      = (const float*)d_in[2];
    float*       out       = (float*)d_out;

    int n = in_sizes[0] / 3;
    size_t need = (size_t)n * N_KER * sizeof(__half);

    if (ws_size >= need) {
        __half* S = (__half*)d_ws;
        int blocks1 = (n + 15) / 16;                   // 4 q/wave, 4 waves
        corr_phase1<<<blocks1, 256, 0, stream>>>(normal, kern, S, n);
        int total2  = n * (N_KER / 2);
        int blocks2 = (total2 + 255) / 256;
        corr_phase2<<<blocks2, 256, 0, stream>>>((const __half2*)S, neighbour,
                                                 (float2*)out, n);
    } else {
        int blocks = (n + 3) / 4;
        corr_fused<<<blocks, 256, 0, stream>>>(normal, neighbour, kern, out, n);
    }
}